// Round 9
// baseline (305.183 us; speedup 1.0000x reference)
//
#include <hip/hip_runtime.h>
#include <math.h>

static constexpr int kN = 8192;
static constexpr int kC = 128;
static constexpr int kB = 16;
static constexpr float kScale = 0.5f / 1048576.0f; // 1/(C*N) * 0.5 (pack fold)
static constexpr double kTwoPi = 6.28318530717958647692;

#define C8  0.70710678118654752f
#define CP8 0.92387953251128676f
#define SP8 0.38268343236508977f
#define TWO_PI_F 6.2831853071795864769f

typedef float v2f __attribute__((ext_vector_type(2)));

__device__ __forceinline__ v2f mk2(float x, float y){ v2f r; r.x=x; r.y=y; return r; }
__device__ __forceinline__ v2f imul(v2f a){ return mk2(-a.y, a.x); }   // +i*a
__device__ __forceinline__ v2f mimul(v2f a){ return mk2(a.y, -a.x); }  // -i*a
__device__ __forceinline__ v2f cconj(v2f a){ return mk2(a.x, -a.y); }
__device__ __forceinline__ v2f cmul(v2f a, v2f b){
    return mk2(a.x*b.x - a.y*b.y, a.x*b.y + a.y*b.x);
}

// e^{+2pi i rev} via HW trans pipe
__device__ __forceinline__ v2f wrev(float rev){
    float s, c;
    __sincosf(rev * TWO_PI_F, &s, &c);
    return mk2(c, s);
}

// swizzle (validated r8): conflict-floor for stride-256 / mixed / stride-16
__device__ __forceinline__ int swz(int n){ return n ^ ((n>>4)&15); }

// slot s = 4j+m holds A[4m+j]; A[k] lives at reg REV(k)
#define REV(k) ((((k)&3)<<2)|((k)>>2))

template<int SGN>
__device__ __forceinline__ void dft4(v2f&a, v2f&b, v2f&c, v2f&d){
    v2f t0=a+c, t1=a-c, t2=b+d, t3=b-d;
    v2f j3 = (SGN>0) ? imul(t3) : mimul(t3);
    a = t0+t2; b = t1+j3; c = t0-t2; d = t1-j3;
}

// 16-pt DFT, A_k = sum_j in[j] e^{SGN*2pi i jk/16}; in natural, out via REV.
template<int SGN>
__device__ __forceinline__ void dft16(v2f* v){
    dft4<SGN>(v[0], v[4], v[8],  v[12]);
    dft4<SGN>(v[1], v[5], v[9],  v[13]);
    dft4<SGN>(v[2], v[6], v[10], v[14]);
    dft4<SGN>(v[3], v[7], v[11], v[15]);
    const float sg = (SGN>0)? 1.f : -1.f;
    const v2f W1 = mk2(CP8,  sg*SP8);
    const v2f W2 = mk2(C8,   sg*C8);
    const v2f W3 = mk2(SP8,  sg*CP8);
    const v2f W6 = mk2(-C8,  sg*C8);
    const v2f W9 = mk2(-CP8, -sg*SP8);
    v[5]  = cmul(v[5],  W1);
    v[9]  = cmul(v[9],  W2);
    v[13] = cmul(v[13], W3);
    v[6]  = cmul(v[6],  W2);
    v[10] = (SGN>0)? imul(v[10]) : mimul(v[10]);
    v[14] = cmul(v[14], W6);
    v[7]  = cmul(v[7],  W3);
    v[11] = cmul(v[11], W6);
    v[15] = cmul(v[15], W9);
    dft4<SGN>(v[0],  v[1],  v[2],  v[3]);
    dft4<SGN>(v[4],  v[5],  v[6],  v[7]);
    dft4<SGN>(v[8],  v[9],  v[10], v[11]);
    dft4<SGN>(v[12], v[13], v[14], v[15]);
}

// DIF twiddle via sincos: A[m] (at reg REV(m)) *= e^{SGN*2pi i q m inv}
template<int SGN>
__device__ __forceinline__ void twid_dif_sc(v2f* v, int q, float inv){
    #pragma unroll
    for (int m = 1; m < 16; ++m) {
        v2f w = wrev((float)(q*m) * inv);
        if (SGN < 0) w = cconj(w);
        v[REV(m)] = cmul(v[REV(m)], w);
    }
}
// DIT twiddle (before dft): v[j] *= e^{SGN*2pi i q j inv}, natural index
template<int SGN>
__device__ __forceinline__ void twid_dit_sc(v2f* v, int q, float inv){
    #pragma unroll
    for (int m = 1; m < 16; ++m) {
        v2f w = wrev((float)(q*m) * inv);
        if (SGN < 0) w = cconj(w);
        v[m] = cmul(v[m], w);
    }
}

// tanh-form GELU on both components
__device__ __forceinline__ v2f gelu2(v2f v){
    v2f z = v * (0.7978845608028654f + 0.0356774081363001f * v * v);
    float e0 = __builtin_amdgcn_exp2f(-2.8853900817779268f * z.x);
    float e1 = __builtin_amdgcn_exp2f(-2.8853900817779268f * z.y);
    return mk2(v.x / (1.0f + e0), v.y / (1.0f + e1));
}

// Kernel 1: one row per 256-thread WG, radix-16^3, 16 elems/thread, NO twiddle
// table (all twiddles via trans-pipe sincos). LDS = 32 KiB -> 5 WG/CU.
// Hermitian-pack -> inverse FFT (A,B,C) -> instnorm+GELU -> forward FFT
// (C',B',A') -> rfft post-combine (mirror via LDS) -> write Y[0..4096].
__global__ __launch_bounds__(256, 5) void k1_row(
    const float* __restrict__ xr, const float* __restrict__ xi,
    const float* __restrict__ gamma, const float* __restrict__ beta,
    float* __restrict__ outR, float* __restrict__ outI)
{
    __shared__ v2f buf[4096];  // 32 KiB, swizzled

    const int p   = threadIdx.x;        // 0..255
    const int row = blockIdx.x;
    const int ch  = row & (kC-1);

    const int i0 = ((p>>4)<<8) + (p&15);  // stage-B group base
    const int qB = p & 15;                 // stage-B twiddle index (W256^qB)

    v2f v[16];

    const float* rR = xr + (size_t)row * kN;
    const float* rI = xi + (size_t)row * kN;

    // ---- pre-combine (0.5 dropped; instnorm absorbs): Z[k], w=e^{+i pi k/4096}
    #pragma unroll
    for (int j = 0; j < 16; ++j) {
        int k   = p + (j<<8);
        int km  = (kN - k) & (kN-1);
        int km2 = 4096 - k;
        v2f w = wrev((float)k * (1.0f/8192.0f));
        v2f Hk  = mk2(rR[k]+rR[km],       rI[k]-rI[km]);
        v2f Hk2 = mk2(rR[k+4096]+rR[km2], rI[k+4096]-rI[km2]);
        v2f S = Hk + Hk2, D = Hk - Hk2;
        v2f P = cmul(D, w);
        v[j] = S + imul(P);                            // 2*Z[k]
    }
    // ---- DIF stage A (h=256), sigma=+1 ----
    dft16<1>(v);
    twid_dif_sc<1>(v, p, 1.0f/4096.0f);
    #pragma unroll
    for (int m = 0; m < 16; ++m) buf[swz(p + (m<<8))] = v[REV(m)];
    __syncthreads();                                  // (1) A -> B

    // ---- DIF stage B (h=16) ----
    #pragma unroll
    for (int j = 0; j < 16; ++j) v[j] = buf[swz(i0 + (j<<4))];
    dft16<1>(v);
    twid_dif_sc<1>(v, qB, 1.0f/256.0f);
    #pragma unroll
    for (int m = 0; m < 16; ++m) buf[swz(i0 + (m<<4))] = v[REV(m)];
    __syncthreads();                                  // (2) B -> C

    // ---- DIF stage C (h=1): thread-private slots {16p+j} ----
    #pragma unroll
    for (int j = 0; j < 16; ++j) v[j] = buf[swz((p<<4) + j)];
    dft16<1>(v);

    // ---- instance norm stats (order-agnostic) ----
    float ps = 0.f, pq = 0.f;
    #pragma unroll
    for (int j = 0; j < 16; ++j) {
        ps += v[j].x + v[j].y;
        pq += v[j].x*v[j].x + v[j].y*v[j].y;
    }
    #pragma unroll
    for (int off = 32; off >= 1; off >>= 1) {
        ps += __shfl_down(ps, off);
        pq += __shfl_down(pq, off);
    }
    if ((p & 63) == 0) buf[swz(p<<4)] = mk2(ps, pq);  // own private slot
    __syncthreads();                                  // (3) partials visible
    float sum = 0.f, sq = 0.f;
    #pragma unroll
    for (int w = 0; w < 4; ++w) {
        v2f pr = buf[swz((w<<6)<<4)];
        sum += pr.x; sq += pr.y;
    }
    __syncthreads();                                  // (4) reads before C' stores
    float mean = sum * (1.0f/8192.0f);
    float var  = sq  * (1.0f/8192.0f) - mean*mean;
    float gg = gamma[ch] * rsqrtf(var + 1e-5f);
    float bb = beta[ch] - mean * gg;
    #pragma unroll
    for (int j = 0; j < 16; ++j) v[j] = gelu2(v[j] * gg + bb);

    // ---- DIT stage C' (h=1): sample at slot 16p+j is v[REV(j)] ----
    {
        v2f u[16];
        #pragma unroll
        for (int j = 0; j < 16; ++j) u[j] = v[REV(j)];
        dft16<-1>(u);
        #pragma unroll
        for (int m = 0; m < 16; ++m) buf[swz((p<<4) + m)] = u[REV(m)];
    }
    __syncthreads();                                  // (5) C' -> B'

    // ---- DIT stage B' ----
    #pragma unroll
    for (int j = 0; j < 16; ++j) v[j] = buf[swz(i0 + (j<<4))];
    twid_dit_sc<-1>(v, qB, 1.0f/256.0f);
    dft16<-1>(v);
    #pragma unroll
    for (int m = 0; m < 16; ++m) buf[swz(i0 + (m<<4))] = v[REV(m)];
    __syncthreads();                                  // (6) B' -> A'

    // ---- DIT stage A': Z'[p+256m] at reg REV(m) (thread-private slots) ----
    #pragma unroll
    for (int j = 0; j < 16; ++j) v[j] = buf[swz(p + (j<<8))];
    twid_dit_sc<-1>(v, p, 1.0f/4096.0f);
    dft16<-1>(v);
    // store Z' for mirror access (same thread-private slots: no barrier needed
    // before the store, only before cross-thread mirror reads)
    #pragma unroll
    for (int m = 0; m < 16; ++m) buf[swz(p + (m<<8))] = v[REV(m)];
    __syncthreads();                                  // (7) Z' -> mirror

    // ---- post-combine: Y[k] = S - i e^{-i pi k/4096} D (2x; fold in k2) ----
    float* oR = outR + (size_t)row * kN;
    float* oI = outI + (size_t)row * kN;
    #pragma unroll
    for (int m = 0; m < 16; ++m) {
        int k = p + (m<<8);
        v2f Z  = v[REV(m)];
        v2f Zm = buf[swz((4096 - k) & 4095)];
        v2f w = cconj(wrev((float)k * (1.0f/8192.0f)));
        v2f S = mk2(Z.x+Zm.x, Z.y-Zm.y);
        v2f D = mk2(Z.x-Zm.x, Z.y+Zm.y);
        v2f Y = S + mimul(cmul(D, w));
        oR[k] = Y.x;  oI[k] = Y.y;
    }
    if (p == 0) {
        oR[4096] = 2.0f*(v[0].x - v[0].y);  // 2*(Re Z'[0] - Im Z'[0])
        oI[4096] = 0.f;
    }
}

// Kernel 2 (r7 version, ~HBM roofline): per (b, 32-wide k tile), kk in [0,4096]:
// 128-pt FFT along c, scale (incl. folded 0.5), bin rules, conj-mirror writes.
__global__ __launch_bounds__(256,4) void k2_col(float* __restrict__ outR,
                                                float* __restrict__ outI)
{
    __shared__ v2f tile[kC][32];  // 32 KiB
    __shared__ v2f tw[64];

    const int tid = threadIdx.x;
    const int k   = tid & 31;
    const int g   = tid >> 5;        // 0..7
    const int b   = blockIdx.y;
    const int kk  = (blockIdx.x << 5) + k;
    const bool valid = (kk <= 4096);

    if (tid < 64) {
        float s, c;
        sincosf((float)(kTwoPi/128.0 * (double)tid), &s, &c);
        tw[tid] = mk2(c, -s);
    }
    float* baseR = outR + (size_t)b * kC * kN;
    float* baseI = outI + (size_t)b * kC * kN;
    for (int c = g; c < kC; c += 8) {
        size_t off = (size_t)c * kN + kk;
        tile[c][k] = valid ? mk2(baseR[off], baseI[off]) : mk2(0.f, 0.f);
    }
    __syncthreads();

    for (int st = 7; st >= 1; --st) {
        const int h = 1 << (st-1);
        #pragma unroll
        for (int s = 0; s < 8; ++s) {
            int q   = g + (s<<3);
            int pos = q & (h-1);
            int i0  = ((q >> (st-1)) << st) + pos;
            int i1  = i0 + h;
            v2f a = tile[i0][k], bb = tile[i1][k];
            v2f w = tw[pos << (7-st)];
            tile[i0][k] = a + bb;
            tile[i1][k] = cmul(a - bb, w);
        }
        __syncthreads();
    }

    if (valid) {
        for (int p = g; p < kC; p += 8) {
            int f = (int)(__brev((unsigned)p) >> 25);
            v2f v = tile[p][k] * kScale;
            size_t off = (size_t)f * kN + kk;
            if (kk == 0 || kk == 4096) {
                baseR[off] = v.x; baseI[off] = 0.f;
            } else {
                baseR[off] = v.x; baseI[off] = v.y;
                size_t offm = (size_t)f * kN + (kN - kk);
                baseR[offm] = v.x; baseI[offm] = -v.y;
            }
        }
    }
}

extern "C" void kernel_launch(void* const* d_in, const int* in_sizes, int n_in,
                              void* d_out, int out_size, void* d_ws, size_t ws_size,
                              hipStream_t stream)
{
    const float* xr    = (const float*)d_in[0];
    const float* xi    = (const float*)d_in[1];
    const float* gamma = (const float*)d_in[2];
    const float* beta  = (const float*)d_in[3];

    float* outR = (float*)d_out;
    float* outI = outR + (size_t)kB * kC * kN;

    k1_row<<<kB * kC, 256, 0, stream>>>(xr, xi, gamma, beta, outR, outI);
    k2_col<<<dim3(129, kB), 256, 0, stream>>>(outR, outI);
}